// Round 12
// baseline (190.650 us; speedup 1.0000x reference)
//
#include <hip/hip_runtime.h>
#include <hip/hip_cooperative_groups.h>
#include <math.h>

namespace cg = cooperative_groups;

// Problem dims (fixed by reference)
constexpr int B_ = 128, T_ = 512, I_ = 1024, H_ = 2048, O_ = 512;

// ws float layout: y[B*I] | Z[B*H]
constexpr int YOFF = 0;
constexpr int ZOFF = B_ * I_;

typedef __attribute__((ext_vector_type(4))) short short4v;
typedef __attribute__((ext_vector_type(8))) short short8v;
typedef __attribute__((ext_vector_type(4))) float float4v;

__device__ inline ushort f2bf(float f) {   // f32->bf16 RNE (R4-proven)
    union { float f; unsigned u; } c; c.f = f;
    return (ushort)((c.u + 0x7FFF + ((c.u >> 16) & 1)) >> 16);
}

// ---------------------------------------------------------------------------
// mm body — VERBATIM R8/R9-proven geometry: BM=128, BN=64, BK=32, builtin
// 16x16x32 MFMA, f32 atomic epilogue. Proven trip counts only (4 and 2).
// ---------------------------------------------------------------------------
template <int KGLOB, int NGLOB, int KCH>
__device__ inline void mm_body(char* smraw, int nb, int kb,
                               const float* __restrict__ A,
                               const float* __restrict__ Bm,
                               float* __restrict__ C) {
    constexpr int BN = 64, BK = 32, PAD = 8;
    ushort (*As)[BK + PAD] = (ushort (*)[BK + PAD])smraw;                       // [128][40]
    ushort (*Bs)[BK + PAD] = (ushort (*)[BK + PAD])(smraw + 128 * (BK + PAD) * 2); // [64][40]

    const int n0    = nb * BN;
    const int kbase = kb * KCH;
    const int tid   = threadIdx.x;
    const int lane  = tid & 63;
    const int w     = tid >> 6;
    const int lo    = lane & 15;
    const int hi    = lane >> 4;

    float4v acc[2][4];
#pragma unroll
    for (int mf = 0; mf < 2; ++mf)
#pragma unroll
        for (int nf = 0; nf < 4; ++nf) acc[mf][nf] = (float4v){0.f, 0.f, 0.f, 0.f};

    for (int k0 = kbase; k0 < kbase + KCH; k0 += BK) {
        {   // stage A tile 128x32: row=tid>>1, half-k=(tid&1)*16
            const int row = tid >> 1;
            const int kh  = (tid & 1) * 16;
            const float* ap = A + (size_t)row * KGLOB + k0 + kh;
#pragma unroll
            for (int j = 0; j < 4; ++j) {
                float4v v = *(const float4v*)(ap + 4 * j);
                short4v s;
                s[0] = (short)f2bf(v.x); s[1] = (short)f2bf(v.y);
                s[2] = (short)f2bf(v.z); s[3] = (short)f2bf(v.w);
                *(short4v*)&As[row][kh + 4 * j] = s;
            }
        }
        {   // stage B tile 32x64 transposed: k=tid>>3, n-chunk=(tid&7)*8
            const int k  = tid >> 3;
            const int nq = (tid & 7) * 8;
            const float* bp = Bm + (size_t)(k0 + k) * NGLOB + n0 + nq;
#pragma unroll
            for (int j = 0; j < 2; ++j) {
                float4v v = *(const float4v*)(bp + 4 * j);
                Bs[nq + 4 * j + 0][k] = f2bf(v.x);
                Bs[nq + 4 * j + 1][k] = f2bf(v.y);
                Bs[nq + 4 * j + 2][k] = f2bf(v.z);
                Bs[nq + 4 * j + 3][k] = f2bf(v.w);
            }
        }
        __syncthreads();
        {
            const int kk = hi * 8;
            short8v a[2], bv[4];
#pragma unroll
            for (int mf = 0; mf < 2; ++mf)
                a[mf] = *(const short8v*)&As[w * 32 + mf * 16 + lo][kk];
#pragma unroll
            for (int nf = 0; nf < 4; ++nf)
                bv[nf] = *(const short8v*)&Bs[nf * 16 + lo][kk];
#pragma unroll
            for (int mf = 0; mf < 2; ++mf)
#pragma unroll
                for (int nf = 0; nf < 4; ++nf)
                    acc[mf][nf] = __builtin_amdgcn_mfma_f32_16x16x32_bf16(
                        a[mf], bv[nf], acc[mf][nf], 0, 0, 0);
        }
        __syncthreads();
    }
#pragma unroll
    for (int mf = 0; mf < 2; ++mf)
#pragma unroll
        for (int nf = 0; nf < 4; ++nf)
#pragma unroll
            for (int i = 0; i < 4; ++i) {
                const int row = w * 32 + mf * 16 + hi * 4 + i;
                const int col = n0 + nf * 16 + lo;
                atomicAdd(&C[(size_t)row * NGLOB + col], acc[mf][nf][i]);
            }
}

// ---------------------------------------------------------------------------
// Cooperative kernel: 512 blocks x 256 threads, 3 phases, 2 grid syncs.
// ---------------------------------------------------------------------------
__global__ __launch_bounds__(256, 2) void coop(const float* __restrict__ x,
                                               const float* __restrict__ Wi,
                                               const float* __restrict__ b_in,
                                               const float* __restrict__ Wo,
                                               const float* __restrict__ b_out,
                                               float* __restrict__ ws,
                                               float* __restrict__ out, float wsum) {
    __shared__ __align__(16) char sm[(128 * 40 + 64 * 40) * 2];   // 15360 B
    const int bid = blockIdx.x, tid = threadIdx.x;

    // ================= P0: wreduce (atomic-free) + Z/out bias init =========
    {
        float* wl = (float*)sm;                       // [512]
        float4v* red = (float4v*)(sm + 2048);         // [256]
        wl[tid]       = (1.f - powf(0.9f, (float)(T_ - tid))) * 10.f;
        wl[tid + 256] = (1.f - powf(0.9f, (float)(T_ - (tid + 256)))) * 10.f;
        // distributed Z init: Z = wsum*b_in (flat 512 floats per block)
#pragma unroll
        for (int k = tid; k < 512; k += 256) {
            const int f = bid * 512 + k;
            ws[ZOFF + f] = wsum * b_in[f & (H_ - 1)];
        }
        // distributed out init: out = T*b_out (first 128 blocks)
        if (bid < 128) {
#pragma unroll
            for (int k = tid; k < 512; k += 256) {
                const int f = bid * 512 + k;
                out[f] = (float)T_ * b_out[f & (O_ - 1)];
            }
        }
        __syncthreads();

        // block (b,q): y[b, q*256 .. q*256+255] = sum_t w_t x[b,t,...]
        const int b = bid >> 2, q = bid & 3;
        const int lane = tid & 63, grp = tid >> 6;
        const float* xp = x + (size_t)b * T_ * I_ + (size_t)grp * I_ + q * 256 + lane * 4;
        float4v acc = {0.f, 0.f, 0.f, 0.f};
#pragma unroll 2
        for (int s8 = 0; s8 < 128; s8 += 8) {
            float4v v[8];
#pragma unroll
            for (int u = 0; u < 8; ++u)
                v[u] = *(const float4v*)(xp + (size_t)(s8 + u) * 4 * I_);
#pragma unroll
            for (int u = 0; u < 8; ++u)
                acc += wl[(s8 + u) * 4 + grp] * v[u];
        }
        red[tid] = acc;
        __syncthreads();
        if (tid < 64) {
            float4v r = red[tid] + red[tid + 64] + red[tid + 128] + red[tid + 192];
            *(float4v*)(ws + YOFF + (size_t)b * I_ + q * 256 + tid * 4) = r;
        }
    }

    cg::this_grid().sync();

    // ================= P1: Z += y @ W_in  (proven 4-iter mm) ================
    if (bid < 256)
        mm_body<I_, H_, 128>(sm, bid & 31, bid >> 5, ws + YOFF, Wi, ws + ZOFF);

    cg::this_grid().sync();

    // ================= P2: out += Z @ W_out  (proven 2-iter mm) =============
    if (bid < 256)
        mm_body<H_, O_, 64>(sm, bid & 7, bid >> 3, ws + ZOFF, Wo, out);
}

// ---------------------------------------------------------------------------
extern "C" void kernel_launch(void* const* d_in, const int* in_sizes, int n_in,
                              void* d_out, int out_size, void* d_ws, size_t ws_size,
                              hipStream_t stream) {
    const float* x     = (const float*)d_in[0];
    const float* W_in  = (const float*)d_in[1];
    const float* b_in  = (const float*)d_in[2];
    const float* W_out = (const float*)d_in[3];
    const float* b_out = (const float*)d_in[4];
    float* out = (float*)d_out;
    float* ws  = (float*)d_ws;

    // wsum = sum_t (1-beta^(T-t))/(1-beta), exact in double on host
    const double beta = 0.9;
    const double bT = pow(beta, (double)T_);
    const float wsum = (float)(((double)T_ - beta * (1.0 - bT) / (1.0 - beta)) / (1.0 - beta));

    void* args[] = {(void*)&x, (void*)&W_in, (void*)&b_in, (void*)&W_out,
                    (void*)&b_out, (void*)&ws, (void*)&out, (void*)&wsum};
    hipLaunchCooperativeKernel((const void*)coop, dim3(512), dim3(256), args, 0, stream);
}

// Round 13
// 76.252 us; speedup vs baseline: 2.5003x; 2.5003x over previous
//
#include <hip/hip_runtime.h>
#include <hip/hip_bf16.h>
#include <math.h>

// Problem dims (fixed by reference)
constexpr int B_ = 128, T_ = 512, I_ = 1024, H_ = 2048, O_ = 512;
#define BETA 0.9f

// ws float layout: w[512] | y[B*I] | Z[B*H]
constexpr int WOFF = 0;
constexpr int YOFF = 512;
constexpr int ZOFF = YOFF + B_ * I_;
constexpr int WS_FLOATS = ZOFF + B_ * H_;

typedef __attribute__((ext_vector_type(4))) short short4v;   // 4 bf16
typedef __attribute__((ext_vector_type(8))) short short8v;   // 8 bf16 (4 VGPR)
typedef __attribute__((ext_vector_type(4))) float float4v;   // 4 f32

// ---------------------------------------------------------------------------
// Kernel 1: init w[t], zero y, Z = wsum*b_in, out = T*b_out  (R9-exact)
// ---------------------------------------------------------------------------
__global__ __launch_bounds__(256) void init_kernel(float* __restrict__ ws,
                                                   const float* __restrict__ b_in,
                                                   const float* __restrict__ b_out,
                                                   float* __restrict__ out, float wsum) {
    int idx = blockIdx.x * 256 + threadIdx.x;
    const int total = WS_FLOATS + B_ * O_;
    if (idx >= total) return;
    if (idx < 512) {
        ws[idx] = (1.0f - powf(BETA, (float)(T_ - idx))) * (1.0f / (1.0f - BETA));
    } else if (idx < ZOFF) {
        ws[idx] = 0.0f;                       // y accumulator
    } else if (idx < WS_FLOATS) {
        int j = idx - ZOFF;
        ws[idx] = wsum * b_in[j & (H_ - 1)];  // Z bias init
    } else {
        int j = idx - WS_FLOATS;
        out[j] = (float)T_ * b_out[j & (O_ - 1)];  // out bias init
    }
}

// ---------------------------------------------------------------------------
// Kernel 2: y[b,i] += sum_{t in chunk} w[t] * x[b,t,i]
// TCH=128 -> grid = 512 blocks. ONLY change vs R9: nontemporal x loads.
// ---------------------------------------------------------------------------
constexpr int TCH = 128;
__global__ __launch_bounds__(256) void wreduce_kernel(const float* __restrict__ x,
                                                      float* __restrict__ ws) {
    __shared__ float wl[TCH];
    const int b  = blockIdx.x >> 2;   // T/TCH = 4 chunks
    const int tc = blockIdx.x & 3;
    const int t0 = tc * TCH;
    if (threadIdx.x < TCH) wl[threadIdx.x] = ws[WOFF + t0 + threadIdx.x];
    __syncthreads();

    const int i = threadIdx.x * 4;
    const float* xp = x + (size_t)b * T_ * I_ + (size_t)t0 * I_ + i;
    float4v acc = {0.f, 0.f, 0.f, 0.f};
#pragma unroll 4
    for (int tb = 0; tb < TCH; tb += 8) {
        float4v v[8];
#pragma unroll
        for (int j = 0; j < 8; ++j)
            v[j] = __builtin_nontemporal_load((const float4v*)(xp + (size_t)(tb + j) * I_));
#pragma unroll
        for (int j = 0; j < 8; ++j) {
            const float wt = wl[tb + j];
            acc.x += wt * v[j].x; acc.y += wt * v[j].y;
            acc.z += wt * v[j].z; acc.w += wt * v[j].w;
        }
    }
    float* yp = ws + YOFF + b * I_ + i;
    atomicAdd(yp + 0, acc.x);
    atomicAdd(yp + 1, acc.y);
    atomicAdd(yp + 2, acc.z);
    atomicAdd(yp + 3, acc.w);
}

// ---------------------------------------------------------------------------
// Kernel 3/4 (R8/R9-proven, verbatim): C[128,N] += A[128,K] @ B[K,N],
// builtin 16x16x32 bf16 MFMA, f32 atomic epilogue. grid = (N/64, K/KCH).
// ---------------------------------------------------------------------------
template <int KGLOB, int NGLOB, int KCH>
__global__ __launch_bounds__(256) void mm128(const float* __restrict__ A,
                                             const float* __restrict__ Bm,
                                             float* __restrict__ C) {
    constexpr int BN = 64, BK = 32, PAD = 8;
    __shared__ __align__(16) __hip_bfloat16 As[128][BK + PAD];  // [row][k]
    __shared__ __align__(16) __hip_bfloat16 Bs[BN][BK + PAD];   // [n][k]

    const int n0    = blockIdx.x * BN;
    const int kbase = blockIdx.y * KCH;
    const int tid   = threadIdx.x;
    const int lane  = tid & 63;
    const int w     = tid >> 6;
    const int lo    = lane & 15;
    const int hi    = lane >> 4;

    float4v acc[2][4];
#pragma unroll
    for (int mf = 0; mf < 2; ++mf)
#pragma unroll
        for (int nf = 0; nf < 4; ++nf) acc[mf][nf] = (float4v){0.f, 0.f, 0.f, 0.f};

    for (int k0 = kbase; k0 < kbase + KCH; k0 += BK) {
        {
            const int row = tid >> 1;
            const int kh  = (tid & 1) * 16;
            const float* ap = A + (size_t)row * KGLOB + k0 + kh;
#pragma unroll
            for (int j = 0; j < 4; ++j) {
                float4 v = *(const float4*)(ap + 4 * j);
                union { short4v s; __hip_bfloat16 h[4]; } u;
                u.h[0] = __float2bfloat16(v.x); u.h[1] = __float2bfloat16(v.y);
                u.h[2] = __float2bfloat16(v.z); u.h[3] = __float2bfloat16(v.w);
                *(short4v*)&As[row][kh + 4 * j] = u.s;
            }
        }
        {
            const int k  = tid >> 3;
            const int nq = (tid & 7) * 8;
            const float* bp = Bm + (size_t)(k0 + k) * NGLOB + n0 + nq;
#pragma unroll
            for (int j = 0; j < 2; ++j) {
                float4 v = *(const float4*)(bp + 4 * j);
                Bs[nq + 4 * j + 0][k] = __float2bfloat16(v.x);
                Bs[nq + 4 * j + 1][k] = __float2bfloat16(v.y);
                Bs[nq + 4 * j + 2][k] = __float2bfloat16(v.z);
                Bs[nq + 4 * j + 3][k] = __float2bfloat16(v.w);
            }
        }
        __syncthreads();
        {
            const int kk = hi * 8;
            short8v a[2], bv[4];
#pragma unroll
            for (int mf = 0; mf < 2; ++mf)
                a[mf] = *(const short8v*)&As[w * 32 + mf * 16 + lo][kk];
#pragma unroll
            for (int nf = 0; nf < 4; ++nf)
                bv[nf] = *(const short8v*)&Bs[nf * 16 + lo][kk];
#pragma unroll
            for (int mf = 0; mf < 2; ++mf)
#pragma unroll
                for (int nf = 0; nf < 4; ++nf)
                    acc[mf][nf] = __builtin_amdgcn_mfma_f32_16x16x32_bf16(
                        a[mf], bv[nf], acc[mf][nf], 0, 0, 0);
        }
        __syncthreads();
    }
#pragma unroll
    for (int mf = 0; mf < 2; ++mf)
#pragma unroll
        for (int nf = 0; nf < 4; ++nf)
#pragma unroll
            for (int i = 0; i < 4; ++i) {
                const int row = w * 32 + mf * 16 + hi * 4 + i;
                const int col = n0 + nf * 16 + lo;
                atomicAdd(&C[(size_t)row * NGLOB + col], acc[mf][nf][i]);
            }
}

// ---------------------------------------------------------------------------
extern "C" void kernel_launch(void* const* d_in, const int* in_sizes, int n_in,
                              void* d_out, int out_size, void* d_ws, size_t ws_size,
                              hipStream_t stream) {
    const float* x     = (const float*)d_in[0];
    const float* W_in  = (const float*)d_in[1];
    const float* b_in  = (const float*)d_in[2];
    const float* W_out = (const float*)d_in[3];
    const float* b_out = (const float*)d_in[4];
    float* out = (float*)d_out;
    float* ws  = (float*)d_ws;

    // wsum = sum_t (1-beta^(T-t))/(1-beta), exact in double on host
    const double beta = 0.9;
    const double bT = pow(beta, (double)T_);
    const float wsum = (float)(((double)T_ - beta * (1.0 - bT) / (1.0 - beta)) / (1.0 - beta));

    const int total = WS_FLOATS + B_ * O_;
    init_kernel<<<(total + 255) / 256, 256, 0, stream>>>(ws, b_in, b_out, out, wsum);

    wreduce_kernel<<<B_ * (T_ / TCH), 256, 0, stream>>>(x, ws);

    // Z = y @ W_in : K=1024, split-K 8 (KCH=128) -> 256 blocks, 4 iters each
    mm128<I_, H_, 128><<<dim3(H_ / 64, I_ / 128), 256, 0, stream>>>(ws + YOFF, W_in, ws + ZOFF);

    // out = Z @ W_out : K=2048, split-K 32 (KCH=64) -> 256 blocks, 2 iters each
    mm128<H_, O_, 64><<<dim3(O_ / 64, H_ / 64), 256, 0, stream>>>(ws + ZOFF, W_out, out);
}

// Round 14
// 74.303 us; speedup vs baseline: 2.5658x; 1.0262x over previous
//
#include <hip/hip_runtime.h>
#include <hip/hip_bf16.h>
#include <math.h>

// Problem dims (fixed by reference)
constexpr int B_ = 128, T_ = 512, I_ = 1024, H_ = 2048, O_ = 512;
#define BETA 0.9f

// ws float layout: w[512] | y[B*I] | Z[B*H]
constexpr int WOFF = 0;
constexpr int YOFF = 512;
constexpr int ZOFF = YOFF + B_ * I_;
constexpr int WS_FLOATS = ZOFF + B_ * H_;

typedef __attribute__((ext_vector_type(4))) short short4v;   // 4 bf16
typedef __attribute__((ext_vector_type(8))) short short8v;   // 8 bf16 (4 VGPR)
typedef __attribute__((ext_vector_type(4))) float float4v;   // 4 f32

// ---------------------------------------------------------------------------
// Kernel 1 (R9-exact): init w[t], zero y, Z = wsum*b_in, out = T*b_out
// ---------------------------------------------------------------------------
__global__ __launch_bounds__(256) void init_kernel(float* __restrict__ ws,
                                                   const float* __restrict__ b_in,
                                                   const float* __restrict__ b_out,
                                                   float* __restrict__ out, float wsum) {
    int idx = blockIdx.x * 256 + threadIdx.x;
    const int total = WS_FLOATS + B_ * O_;
    if (idx >= total) return;
    if (idx < 512) {
        ws[idx] = (1.0f - powf(BETA, (float)(T_ - idx))) * (1.0f / (1.0f - BETA));
    } else if (idx < ZOFF) {
        ws[idx] = 0.0f;                       // y accumulator
    } else if (idx < WS_FLOATS) {
        int j = idx - ZOFF;
        ws[idx] = wsum * b_in[j & (H_ - 1)];  // Z bias init
    } else {
        int j = idx - WS_FLOATS;
        out[j] = (float)T_ * b_out[j & (O_ - 1)];  // out bias init
    }
}

// ---------------------------------------------------------------------------
// Kernel 2: y[b,i] += sum_{t in chunk} w[t] * x[b,t,i]
// ONLY change vs R9: I-dimension split in half -> grid = B*4*2 = 1024 blocks
// (16 waves/CU, was 8) at the SAME 4-way atomic contention. Each block:
// two 128-thread groups handle the t-pair (sub=0/1), pair-reduced in LDS
// before one atomicAdd per (i4).
// ---------------------------------------------------------------------------
constexpr int TCH = 128;
__global__ __launch_bounds__(256) void wreduce_kernel(const float* __restrict__ x,
                                                      float* __restrict__ ws) {
    __shared__ float wl[TCH];
    __shared__ float4v red[256];
    const int bid = blockIdx.x;
    const int b  = bid >> 3;           // 128 b
    const int tc = (bid >> 1) & 3;     // 4 t-chunks
    const int q  = bid & 1;            // 2 i-halves
    const int t0 = tc * TCH;
    if (threadIdx.x < TCH) wl[threadIdx.x] = ws[WOFF + t0 + threadIdx.x];
    __syncthreads();

    const int sub = threadIdx.x >> 7;  // 0/1: which t of each pair
    const int l   = threadIdx.x & 127; // i-lane within the half
    const int i   = q * 512 + l * 4;
    const float* xp = x + (size_t)b * T_ * I_ + (size_t)(t0 + sub) * I_ + i;
    float4v acc = {0.f, 0.f, 0.f, 0.f};
#pragma unroll 4
    for (int tt = 0; tt < TCH; tt += 16) {    // 16 t per batch = 8 per sub
        float4v v[8];
#pragma unroll
        for (int j = 0; j < 8; ++j)
            v[j] = *(const float4v*)(xp + (size_t)(tt + 2 * j) * I_);
#pragma unroll
        for (int j = 0; j < 8; ++j)
            acc += wl[tt + 2 * j + sub] * v[j];
    }
    red[threadIdx.x] = acc;
    __syncthreads();
    if (threadIdx.x < 128) {
        float4v r = red[threadIdx.x] + red[threadIdx.x + 128];
        float* yp = ws + YOFF + (size_t)b * I_ + i;
        atomicAdd(yp + 0, r.x);
        atomicAdd(yp + 1, r.y);
        atomicAdd(yp + 2, r.z);
        atomicAdd(yp + 3, r.w);
    }
}

// ---------------------------------------------------------------------------
// Kernel 3/4 (R8/R9-proven, verbatim): C[128,N] += A[128,K] @ B[K,N],
// builtin 16x16x32 bf16 MFMA, f32 atomic epilogue. grid = (N/64, K/KCH).
// ---------------------------------------------------------------------------
template <int KGLOB, int NGLOB, int KCH>
__global__ __launch_bounds__(256) void mm128(const float* __restrict__ A,
                                             const float* __restrict__ Bm,
                                             float* __restrict__ C) {
    constexpr int BN = 64, BK = 32, PAD = 8;
    __shared__ __align__(16) __hip_bfloat16 As[128][BK + PAD];  // [row][k]
    __shared__ __align__(16) __hip_bfloat16 Bs[BN][BK + PAD];   // [n][k]

    const int n0    = blockIdx.x * BN;
    const int kbase = blockIdx.y * KCH;
    const int tid   = threadIdx.x;
    const int lane  = tid & 63;
    const int w     = tid >> 6;
    const int lo    = lane & 15;
    const int hi    = lane >> 4;

    float4v acc[2][4];
#pragma unroll
    for (int mf = 0; mf < 2; ++mf)
#pragma unroll
        for (int nf = 0; nf < 4; ++nf) acc[mf][nf] = (float4v){0.f, 0.f, 0.f, 0.f};

    for (int k0 = kbase; k0 < kbase + KCH; k0 += BK) {
        {
            const int row = tid >> 1;
            const int kh  = (tid & 1) * 16;
            const float* ap = A + (size_t)row * KGLOB + k0 + kh;
#pragma unroll
            for (int j = 0; j < 4; ++j) {
                float4 v = *(const float4*)(ap + 4 * j);
                union { short4v s; __hip_bfloat16 h[4]; } u;
                u.h[0] = __float2bfloat16(v.x); u.h[1] = __float2bfloat16(v.y);
                u.h[2] = __float2bfloat16(v.z); u.h[3] = __float2bfloat16(v.w);
                *(short4v*)&As[row][kh + 4 * j] = u.s;
            }
        }
        {
            const int k  = tid >> 3;
            const int nq = (tid & 7) * 8;
            const float* bp = Bm + (size_t)(k0 + k) * NGLOB + n0 + nq;
#pragma unroll
            for (int j = 0; j < 2; ++j) {
                float4 v = *(const float4*)(bp + 4 * j);
                Bs[nq + 4 * j + 0][k] = __float2bfloat16(v.x);
                Bs[nq + 4 * j + 1][k] = __float2bfloat16(v.y);
                Bs[nq + 4 * j + 2][k] = __float2bfloat16(v.z);
                Bs[nq + 4 * j + 3][k] = __float2bfloat16(v.w);
            }
        }
        __syncthreads();
        {
            const int kk = hi * 8;
            short8v a[2], bv[4];
#pragma unroll
            for (int mf = 0; mf < 2; ++mf)
                a[mf] = *(const short8v*)&As[w * 32 + mf * 16 + lo][kk];
#pragma unroll
            for (int nf = 0; nf < 4; ++nf)
                bv[nf] = *(const short8v*)&Bs[nf * 16 + lo][kk];
#pragma unroll
            for (int mf = 0; mf < 2; ++mf)
#pragma unroll
                for (int nf = 0; nf < 4; ++nf)
                    acc[mf][nf] = __builtin_amdgcn_mfma_f32_16x16x32_bf16(
                        a[mf], bv[nf], acc[mf][nf], 0, 0, 0);
        }
        __syncthreads();
    }
#pragma unroll
    for (int mf = 0; mf < 2; ++mf)
#pragma unroll
        for (int nf = 0; nf < 4; ++nf)
#pragma unroll
            for (int i = 0; i < 4; ++i) {
                const int row = w * 32 + mf * 16 + hi * 4 + i;
                const int col = n0 + nf * 16 + lo;
                atomicAdd(&C[(size_t)row * NGLOB + col], acc[mf][nf][i]);
            }
}

// ---------------------------------------------------------------------------
extern "C" void kernel_launch(void* const* d_in, const int* in_sizes, int n_in,
                              void* d_out, int out_size, void* d_ws, size_t ws_size,
                              hipStream_t stream) {
    const float* x     = (const float*)d_in[0];
    const float* W_in  = (const float*)d_in[1];
    const float* b_in  = (const float*)d_in[2];
    const float* W_out = (const float*)d_in[3];
    const float* b_out = (const float*)d_in[4];
    float* out = (float*)d_out;
    float* ws  = (float*)d_ws;

    // wsum = sum_t (1-beta^(T-t))/(1-beta), exact in double on host
    const double beta = 0.9;
    const double bT = pow(beta, (double)T_);
    const float wsum = (float)(((double)T_ - beta * (1.0 - bT) / (1.0 - beta)) / (1.0 - beta));

    const int total = WS_FLOATS + B_ * O_;
    init_kernel<<<(total + 255) / 256, 256, 0, stream>>>(ws, b_in, b_out, out, wsum);

    wreduce_kernel<<<B_ * 4 * 2, 256, 0, stream>>>(x, ws);

    // Z = y @ W_in : K=1024, split-K 8 (KCH=128) -> 256 blocks, 4 iters each
    mm128<I_, H_, 128><<<dim3(H_ / 64, I_ / 128), 256, 0, stream>>>(ws + YOFF, W_in, ws + ZOFF);

    // out = Z @ W_out : K=2048, split-K 32 (KCH=64) -> 256 blocks, 2 iters each
    mm128<H_, O_, 64><<<dim3(O_ / 64, H_ / 64), 256, 0, stream>>>(ws + ZOFF, W_out, out);
}